// Round 4
// baseline (82.353 us; speedup 1.0000x reference)
//
#include <hip/hip_runtime.h>

#define BS 16
#define CH 256
#define TT 2048
#define NBINS 512   // 16 batches x 32 start-buckets

// ---------------------------------------------------------------------------
// Sort body: bin ROIs by (batch, start-bucket). 256 threads, one block.
// LDS hist + wave scan + scatter. Within-bin order is atomic-arrival
// (nondeterministic) but each ROI's output is order-independent -> d_out
// deterministic.
// ---------------------------------------------------------------------------
__device__ void ROIAlign_sort_body(const float* __restrict__ rois, int N,
                                   int* __restrict__ perm, int tid)
{
    __shared__ int hist[NBINS];
    __shared__ int waveSums[4];

    for (int i = tid; i < NBINS; i += 256) hist[i] = 0;
    __syncthreads();

    for (int n = tid; n < N; n += 256) {
        const int   b  = (int)rois[3 * n];
        const float s  = rois[3 * n + 1];
        const int   sb = min(31, max(0, (int)(s * (1.0f / 64.0f))));  // TT/32=64
        atomicAdd(&hist[b * 32 + sb], 1);
    }
    __syncthreads();

    // thread t owns bins 2t, 2t+1; wave-scan pair sums, serial wave offsets
    const int a0  = hist[2 * tid];
    const int a1  = hist[2 * tid + 1];
    const int own = a0 + a1;
    int v = own;
    #pragma unroll
    for (int d = 1; d < 64; d <<= 1) {
        int u = __shfl_up(v, d, 64);
        if ((tid & 63) >= d) v += u;
    }
    if ((tid & 63) == 63) waveSums[tid >> 6] = v;
    __syncthreads();
    if (tid == 0) {
        int run = 0;
        #pragma unroll
        for (int i = 0; i < 4; ++i) { int c = waveSums[i]; waveSums[i] = run; run += c; }
    }
    __syncthreads();
    const int excl = v - own + waveSums[tid >> 6];
    hist[2 * tid]     = excl;
    hist[2 * tid + 1] = excl + a0;
    __syncthreads();

    for (int n = tid; n < N; n += 256) {
        const int   b  = (int)rois[3 * n];
        const float s  = rois[3 * n + 1];
        const int   sb = min(31, max(0, (int)(s * (1.0f / 64.0f))));
        const int pos = atomicAdd(&hist[b * 32 + sb], 1);
        perm[pos] = n;
    }
}

// ---------------------------------------------------------------------------
// Transpose (BS, CH, TT) -> (BS, TT, CH), with the sort block folded into the
// same launch (blockIdx.z == BS, block (0,0,BS)) so the ~8us single-CU sort
// runs concurrently with the 8191 transpose blocks instead of serially.
// ---------------------------------------------------------------------------
__global__ __launch_bounds__(256) void ROIAlign_transpose_sort_kernel(
    const float* __restrict__ in, float* __restrict__ outT,
    const float* __restrict__ rois, int N, int* __restrict__ perm)
{
    const int tx = threadIdx.x;      // 0..31
    const int ty = threadIdx.y;      // 0..7

    if (blockIdx.z == BS) {
        if (blockIdx.x == 0 && blockIdx.y == 0 && perm)
            ROIAlign_sort_body(rois, N, perm, ty * 32 + tx);
        return;
    }

    __shared__ float tile[32][33];
    const int b  = blockIdx.z;
    const int t0 = blockIdx.x * 32;
    const int c0 = blockIdx.y * 32;

    const float* p = in + ((size_t)b * CH + c0) * TT + t0;
    #pragma unroll
    for (int i = ty; i < 32; i += 8)
        tile[i][tx] = p[(size_t)i * TT + tx];

    __syncthreads();

    float* q = outT + ((size_t)b * TT + t0) * CH + c0;
    #pragma unroll
    for (int i = ty; i < 32; i += 8)
        q[(size_t)i * CH + tx] = tile[tx][i];
}

// ---------------------------------------------------------------------------
// Main kernel, fd == 32, ratio==2 fast path. Lane l owns channels 4l..4l+3,
// wave w owns f-bins 8w..8w+7. R3 left VGPR=28 (~2 loads in flight ->
// latency-bound). Now: per 4-bin group, 16 float4 loads are staged into
// statically-indexed arrays and pinned above their consumers with
// sched_barrier -> 16 wave-loads in flight per wave.
// ---------------------------------------------------------------------------
__global__ __launch_bounds__(256) void ROIAlign_fd32_kernel(
    const float* __restrict__ inT,     // (BS, TT, CH)
    const float* __restrict__ rois,    // (N, 3)
    const int*   __restrict__ ratio_p,
    const int*   __restrict__ perm,    // may be null
    float*       __restrict__ out)     // (N, CH, 32)
{
    int m;
    if (perm) {
        const int chunk = gridDim.x >> 3;   // XCD-contiguous mapping
        const int sidx  = (blockIdx.x & 7) * chunk + (blockIdx.x >> 3);
        m = perm[sidx];
    } else {
        m = blockIdx.x;
    }
    const int tid = threadIdx.x;

    const int   b      = (int)rois[3 * m + 0];
    const float bstart = rois[3 * m + 1];
    const float bend   = rois[3 * m + 2];
    const float roi_len = fmaxf(bend - bstart, 1.0f);
    const float bin     = roi_len * (1.0f / 32.0f);
    const int   ratio   = ratio_p[0];

    if (ratio == 2) {
        const int w = tid >> 6;
        const int l = tid & 63;
        const float* base = inT + (size_t)b * (TT * CH) + 4 * l;

        float acc[8][4];
        #pragma unroll
        for (int i = 0; i < 8; ++i)
            #pragma unroll
            for (int j = 0; j < 4; ++j) acc[i][j] = 0.0f;

        #pragma unroll
        for (int g = 0; g < 2; ++g) {            // 4 bins per group
            float4 vlo[8], vhi[8];
            float  fr[8], wv[8];
            #pragma unroll
            for (int p = 0; p < 8; ++p) {        // pair p: bin g*4+(p>>1), r=p&1
                const int   i = g * 4 + (p >> 1);
                const float t = bstart +
                    ((float)(w * 8 + i) + ((p & 1) ? 0.75f : 0.25f)) * bin;
                wv[p] = (t >= -1.0f && t <= (float)TT) ? 0.5f : 0.0f;
                float tc = fminf(fmaxf(t, 0.0f), (float)(TT - 1));
                int   lo = (int)tc;
                int   hi = min(lo + 1, TT - 1);
                fr[p] = tc - (float)lo;
                vlo[p] = *(const float4*)(base + (size_t)lo * CH);
                vhi[p] = *(const float4*)(base + (size_t)hi * CH);
            }
            __builtin_amdgcn_sched_barrier(0);   // keep the 16 loads clustered
            #pragma unroll
            for (int p = 0; p < 8; ++p) {
                const int i = g * 4 + (p >> 1);
                acc[i][0] += wv[p] * (vlo[p].x + fr[p] * (vhi[p].x - vlo[p].x));
                acc[i][1] += wv[p] * (vlo[p].y + fr[p] * (vhi[p].y - vlo[p].y));
                acc[i][2] += wv[p] * (vlo[p].z + fr[p] * (vhi[p].z - vlo[p].z));
                acc[i][3] += wv[p] * (vlo[p].w + fr[p] * (vhi[p].w - vlo[p].w));
            }
        }

        float* o = out + ((size_t)m * CH + 4 * l) * 32 + w * 8;
        #pragma unroll
        for (int j = 0; j < 4; ++j) {
            *(float4*)(o + (size_t)j * 32) =
                make_float4(acc[0][j], acc[1][j], acc[2][j], acc[3][j]);
            *(float4*)(o + (size_t)j * 32 + 4) =
                make_float4(acc[4][j], acc[5][j], acc[6][j], acc[7][j]);
        }
    } else {
        const int c = tid;
        const float inv_ratio = 1.0f / (float)ratio;
        const float* base = inT + (size_t)b * (TT * CH) + c;
        for (int f = 0; f < 32; ++f) {
            float a = 0.0f;
            for (int r = 0; r < ratio; ++r) {
                const float off = (float)f + ((float)r + 0.5f) * inv_ratio;
                const float t   = bstart + off * bin;
                if (t >= -1.0f && t <= (float)TT) {
                    float tc = fminf(fmaxf(t, 0.0f), (float)(TT - 1));
                    int   lo = (int)tc;
                    int   hi = min(lo + 1, TT - 1);
                    float fr2 = tc - (float)lo;
                    a += base[(size_t)lo * CH] * (1.0f - fr2)
                       + base[(size_t)hi * CH] * fr2;
                }
            }
            out[((size_t)m * CH + c) * 32 + f] = a * inv_ratio;
        }
    }
}

// ---------------------------------------------------------------------------
// Generic fallback (any fd, no transpose).
// ---------------------------------------------------------------------------
__global__ __launch_bounds__(256) void ROIAlign_generic_kernel(
    const float* __restrict__ in,      // (BS, CH, TT)
    const float* __restrict__ rois,
    const int*   __restrict__ ratio_p,
    float*       __restrict__ out,     // (N, CH, fd)
    int fd)
{
    const int n = blockIdx.x;
    const int   ratio     = ratio_p[0];
    const float inv_ratio = 1.0f / (float)ratio;

    const int   b      = (int)rois[3 * n + 0];
    const float bstart = rois[3 * n + 1];
    const float bend   = rois[3 * n + 2];
    const float roi_len = fmaxf(bend - bstart, 1.0f);
    const float bin     = roi_len / (float)fd;

    const int total = CH * fd;
    for (int idx = threadIdx.x; idx < total; idx += blockDim.x) {
        const int c = idx / fd;
        const int f = idx % fd;
        const float* base = in + ((size_t)b * CH + c) * TT;
        float a = 0.0f;
        for (int r = 0; r < ratio; ++r) {
            const float off = (float)f + ((float)r + 0.5f) * inv_ratio;
            const float t   = bstart + off * bin;
            if (t >= -1.0f && t <= (float)TT) {
                float tc = fminf(fmaxf(t, 0.0f), (float)(TT - 1));
                int   lo = (int)tc;
                int   hi = min(lo + 1, TT - 1);
                float fr = tc - (float)lo;
                a += base[lo] * (1.0f - fr) + base[hi] * fr;
            }
        }
        out[(size_t)n * total + idx] = a * inv_ratio;
    }
}

extern "C" void kernel_launch(void* const* d_in, const int* in_sizes, int n_in,
                              void* d_out, int out_size, void* d_ws, size_t ws_size,
                              hipStream_t stream) {
    const float* in      = (const float*)d_in[0];
    const float* rois    = (const float*)d_in[1];
    const int*   ratio_p = (const int*)d_in[3];
    float*       out     = (float*)d_out;

    const int N  = in_sizes[1] / 3;
    const int fd = out_size / (N * CH);
    const size_t transpose_bytes = (size_t)BS * CH * TT * sizeof(float);
    const size_t perm_bytes      = (size_t)N * sizeof(int);

    const bool fast = (fd == 32) &&
                      (ws_size >= transpose_bytes) &&
                      (in_sizes[0] == BS * CH * TT);

    if (fast) {
        float* inT = (float*)d_ws;
        const bool sorted = (ws_size >= transpose_bytes + perm_bytes) &&
                            (N % 8 == 0) && (N <= 1 << 20);
        int* perm = sorted ? (int*)((char*)d_ws + transpose_bytes) : nullptr;

        dim3 tb(32, 8, 1);
        dim3 tg(TT / 32, CH / 32, BS + (sorted ? 1 : 0));
        hipLaunchKernelGGL(ROIAlign_transpose_sort_kernel, tg, tb, 0, stream,
                           in, inT, rois, N, perm);
        hipLaunchKernelGGL(ROIAlign_fd32_kernel, dim3(N), dim3(256), 0, stream,
                           inT, rois, ratio_p, perm, out);
    } else {
        hipLaunchKernelGGL(ROIAlign_generic_kernel, dim3(N), dim3(256), 0, stream,
                           in, rois, ratio_p, out, fd);
    }
}

// Round 5
// 53.924 us; speedup vs baseline: 1.5272x; 1.5272x over previous
//
#include <hip/hip_runtime.h>
#include <hip/hip_bf16.h>

#define BS 16
#define CH 256
#define TT 2048
#define NBINS 512   // 16 batches x 32 start-buckets

typedef unsigned short ushortv8 __attribute__((ext_vector_type(8)));

// ---------------------------------------------------------------------------
// Sort body: bin ROIs by (batch, start-bucket). 256 threads, one block.
// Within-bin order is atomic-arrival (nondeterministic) but each ROI's output
// is order-independent -> d_out deterministic.
// ---------------------------------------------------------------------------
__device__ void ROIAlign_sort_body(const float* __restrict__ rois, int N,
                                   int* __restrict__ perm, int tid)
{
    __shared__ int hist[NBINS];
    __shared__ int waveSums[4];

    for (int i = tid; i < NBINS; i += 256) hist[i] = 0;
    __syncthreads();

    for (int n = tid; n < N; n += 256) {
        const int   b  = (int)rois[3 * n];
        const float s  = rois[3 * n + 1];
        const int   sb = min(31, max(0, (int)(s * (1.0f / 64.0f))));  // TT/32=64
        atomicAdd(&hist[b * 32 + sb], 1);
    }
    __syncthreads();

    const int a0  = hist[2 * tid];
    const int a1  = hist[2 * tid + 1];
    const int own = a0 + a1;
    int v = own;
    #pragma unroll
    for (int d = 1; d < 64; d <<= 1) {
        int u = __shfl_up(v, d, 64);
        if ((tid & 63) >= d) v += u;
    }
    if ((tid & 63) == 63) waveSums[tid >> 6] = v;
    __syncthreads();
    if (tid == 0) {
        int run = 0;
        #pragma unroll
        for (int i = 0; i < 4; ++i) { int c = waveSums[i]; waveSums[i] = run; run += c; }
    }
    __syncthreads();
    const int excl = v - own + waveSums[tid >> 6];
    hist[2 * tid]     = excl;
    hist[2 * tid + 1] = excl + a0;
    __syncthreads();

    for (int n = tid; n < N; n += 256) {
        const int   b  = (int)rois[3 * n];
        const float s  = rois[3 * n + 1];
        const int   sb = min(31, max(0, (int)(s * (1.0f / 64.0f))));
        const int pos = atomicAdd(&hist[b * 32 + sb], 1);
        perm[pos] = n;
    }
}

// ---------------------------------------------------------------------------
// Transpose (BS, CH, TT) f32 -> (BS, TT+1, CH) bf16 (row TT = dup of TT-1 so
// hi = lo+1 is unconditionally safe in the gather). Sort block folded in at
// blockIdx.z == BS so its ~8us runs concurrently on one CU.
// ---------------------------------------------------------------------------
__global__ __launch_bounds__(256) void ROIAlign_transpose_sort_kernel(
    const float* __restrict__ in, __hip_bfloat16* __restrict__ outT,
    const float* __restrict__ rois, int N, int* __restrict__ perm)
{
    const int tx = threadIdx.x;      // 0..31
    const int ty = threadIdx.y;      // 0..7

    if (blockIdx.z == BS) {
        if (blockIdx.x == 0 && blockIdx.y == 0 && perm)
            ROIAlign_sort_body(rois, N, perm, ty * 32 + tx);
        return;
    }

    __shared__ float tile[32][33];
    const int b  = blockIdx.z;
    const int t0 = blockIdx.x * 32;
    const int c0 = blockIdx.y * 32;

    const float* p = in + ((size_t)b * CH + c0) * TT + t0;
    #pragma unroll
    for (int i = ty; i < 32; i += 8)
        tile[i][tx] = p[(size_t)i * TT + tx];    // coalesced along t

    __syncthreads();

    __hip_bfloat16* q = outT + ((size_t)b * (TT + 1) + t0) * CH + c0;
    #pragma unroll
    for (int i = ty; i < 32; i += 8)
        q[(size_t)i * CH + tx] = __float2bfloat16(tile[tx][i]);   // row t0+i, ch c0+tx
    if (t0 == TT - 32 && ty == 7)
        q[(size_t)32 * CH + tx] = __float2bfloat16(tile[tx][31]); // pad row TT
}

// ---------------------------------------------------------------------------
// Main kernel, fd==32, ratio==2 fast path, bf16 gather rows (512B each).
// Wave w owns f-bins 8w..8w+7; half-wave owns 4 bins (lanes 0-31: bins
// 8w..8w+3, lanes 32-63: 8w+4..8w+7); lane covers 8 channels (ushort8=16B).
// One 64-lane load = two 512B rows (one per half-wave's current tap) ->
// 64 loads/block vs 128, and half the L1/L2 bytes. Interp in f32.
// ---------------------------------------------------------------------------
__global__ __launch_bounds__(256) void ROIAlign_fd32_kernel(
    const __hip_bfloat16* __restrict__ inT,   // (BS, TT+1, CH) bf16
    const float* __restrict__ rois,           // (N, 3)
    const int*   __restrict__ ratio_p,
    const int*   __restrict__ perm,           // may be null
    float*       __restrict__ out)            // (N, CH, 32) f32
{
    int m;
    if (perm) {
        const int chunk = gridDim.x >> 3;     // XCD-contiguous mapping
        const int sidx  = (blockIdx.x & 7) * chunk + (blockIdx.x >> 3);
        m = perm[sidx];
    } else {
        m = blockIdx.x;
    }
    const int tid = threadIdx.x;

    const int   b      = (int)rois[3 * m + 0];
    const float bstart = rois[3 * m + 1];
    const float bend   = rois[3 * m + 2];
    const float roi_len = fmaxf(bend - bstart, 1.0f);
    const float binsz   = roi_len * (1.0f / 32.0f);
    const int   ratio   = ratio_p[0];

    if (ratio == 2) {
        const int w    = tid >> 6;            // wave -> f-bin block
        const int l    = tid & 63;
        const int half = l >> 5;              // 0: bins +0..3, 1: bins +4..7
        const int lc   = l & 31;              // channel block: ch 8lc..8lc+7

        const unsigned short* base =
            (const unsigned short*)inT + (size_t)b * (TT + 1) * CH + 8 * lc;

        float acc[4][8];
        #pragma unroll
        for (int g = 0; g < 4; ++g)
            #pragma unroll
            for (int j = 0; j < 8; ++j) acc[g][j] = 0.0f;

        #pragma unroll
        for (int g = 0; g < 4; ++g) {
            const float fbin = (float)(w * 8 + half * 4 + g);
            #pragma unroll
            for (int r = 0; r < 2; ++r) {
                const float t  = bstart + (fbin + (r ? 0.75f : 0.25f)) * binsz;
                const float wv = (t >= -1.0f && t <= (float)TT) ? 0.5f : 0.0f;
                float tc = fminf(fmaxf(t, 0.0f), (float)(TT - 1));
                int   lo = (int)tc;           // tc>=0: trunc==floor
                float fr = tc - (float)lo;
                // hi = lo+1 always valid: row TT duplicates TT-1
                const ushortv8 ulo = *(const ushortv8*)(base + (size_t)lo * CH);
                const ushortv8 uhi = *(const ushortv8*)(base + (size_t)(lo + 1) * CH);
                #pragma unroll
                for (int j = 0; j < 8; ++j) {
                    const float vl = __uint_as_float((unsigned)ulo[j] << 16);
                    const float vh = __uint_as_float((unsigned)uhi[j] << 16);
                    acc[g][j] += wv * (vl + fr * (vh - vl));
                }
            }
        }

        // ch 8lc+j gets bins [8w+4*half, +4): one float4 store per channel
        float* o = out + ((size_t)m * CH + 8 * lc) * 32 + w * 8 + half * 4;
        #pragma unroll
        for (int j = 0; j < 8; ++j)
            *(float4*)(o + (size_t)j * 32) =
                make_float4(acc[0][j], acc[1][j], acc[2][j], acc[3][j]);
    } else {
        // generic-ratio path: thread = channel, scalar bf16 taps
        const int c = tid;
        const float inv_ratio = 1.0f / (float)ratio;
        const unsigned short* base =
            (const unsigned short*)inT + (size_t)b * (TT + 1) * CH + c;
        for (int f = 0; f < 32; ++f) {
            float a = 0.0f;
            for (int r = 0; r < ratio; ++r) {
                const float off = (float)f + ((float)r + 0.5f) * inv_ratio;
                const float t   = bstart + off * binsz;
                if (t >= -1.0f && t <= (float)TT) {
                    float tc = fminf(fmaxf(t, 0.0f), (float)(TT - 1));
                    int   lo = (int)tc;
                    float fr = tc - (float)lo;
                    const float vl = __uint_as_float((unsigned)base[(size_t)lo * CH] << 16);
                    const float vh = __uint_as_float((unsigned)base[(size_t)(lo + 1) * CH] << 16);
                    a += vl * (1.0f - fr) + vh * fr;
                }
            }
            out[((size_t)m * CH + c) * 32 + f] = a * inv_ratio;
        }
    }
}

// ---------------------------------------------------------------------------
// Generic fallback (any fd, no transpose, reads original f32 layout).
// ---------------------------------------------------------------------------
__global__ __launch_bounds__(256) void ROIAlign_generic_kernel(
    const float* __restrict__ in,      // (BS, CH, TT)
    const float* __restrict__ rois,
    const int*   __restrict__ ratio_p,
    float*       __restrict__ out,     // (N, CH, fd)
    int fd)
{
    const int n = blockIdx.x;
    const int   ratio     = ratio_p[0];
    const float inv_ratio = 1.0f / (float)ratio;

    const int   b      = (int)rois[3 * n + 0];
    const float bstart = rois[3 * n + 1];
    const float bend   = rois[3 * n + 2];
    const float roi_len = fmaxf(bend - bstart, 1.0f);
    const float bin     = roi_len / (float)fd;

    const int total = CH * fd;
    for (int idx = threadIdx.x; idx < total; idx += blockDim.x) {
        const int c = idx / fd;
        const int f = idx % fd;
        const float* base = in + ((size_t)b * CH + c) * TT;
        float a = 0.0f;
        for (int r = 0; r < ratio; ++r) {
            const float off = (float)f + ((float)r + 0.5f) * inv_ratio;
            const float t   = bstart + off * bin;
            if (t >= -1.0f && t <= (float)TT) {
                float tc = fminf(fmaxf(t, 0.0f), (float)(TT - 1));
                int   lo = (int)tc;
                int   hi = min(lo + 1, TT - 1);
                float fr = tc - (float)lo;
                a += base[lo] * (1.0f - fr) + base[hi] * fr;
            }
        }
        out[(size_t)n * total + idx] = a * inv_ratio;
    }
}

extern "C" void kernel_launch(void* const* d_in, const int* in_sizes, int n_in,
                              void* d_out, int out_size, void* d_ws, size_t ws_size,
                              hipStream_t stream) {
    const float* in      = (const float*)d_in[0];
    const float* rois    = (const float*)d_in[1];
    const int*   ratio_p = (const int*)d_in[3];
    float*       out     = (float*)d_out;

    const int N  = in_sizes[1] / 3;
    const int fd = out_size / (N * CH);
    const size_t transpose_bytes = (size_t)BS * (TT + 1) * CH * sizeof(__hip_bfloat16);
    const size_t perm_bytes      = (size_t)N * sizeof(int);

    const bool fast = (fd == 32) &&
                      (ws_size >= transpose_bytes + perm_bytes) &&
                      (in_sizes[0] == BS * CH * TT);

    if (fast) {
        __hip_bfloat16* inT = (__hip_bfloat16*)d_ws;
        const bool sorted = (N % 8 == 0) && (N <= 1 << 20);
        int* perm = sorted ? (int*)((char*)d_ws + transpose_bytes) : nullptr;

        dim3 tb(32, 8, 1);
        dim3 tg(TT / 32, CH / 32, BS + (sorted ? 1 : 0));
        hipLaunchKernelGGL(ROIAlign_transpose_sort_kernel, tg, tb, 0, stream,
                           in, inT, rois, N, perm);
        hipLaunchKernelGGL(ROIAlign_fd32_kernel, dim3(N), dim3(256), 0, stream,
                           inT, rois, ratio_p, perm, out);
    } else {
        hipLaunchKernelGGL(ROIAlign_generic_kernel, dim3(N), dim3(256), 0, stream,
                           in, rois, ratio_p, out, fd);
    }
}

// Round 6
// 49.629 us; speedup vs baseline: 1.6594x; 1.0865x over previous
//
#include <hip/hip_runtime.h>
#include <hip/hip_bf16.h>

#define BS 16
#define CH 256
#define TT 2048
#define NBINS 512   // 16 batches x 32 start-buckets

typedef unsigned short ushortv8 __attribute__((ext_vector_type(8)));

// ---------------------------------------------------------------------------
// Sort body: bin ROIs by (batch, start-bucket). 256 threads, one block.
// Within-bin order is atomic-arrival (nondeterministic) but each ROI's output
// is order-independent -> d_out deterministic.
// ---------------------------------------------------------------------------
__device__ void ROIAlign_sort_body(const float* __restrict__ rois, int N,
                                   int* __restrict__ perm, int tid)
{
    __shared__ int hist[NBINS];
    __shared__ int waveSums[4];

    for (int i = tid; i < NBINS; i += 256) hist[i] = 0;
    __syncthreads();

    for (int n = tid; n < N; n += 256) {
        const int   b  = (int)rois[3 * n];
        const float s  = rois[3 * n + 1];
        const int   sb = min(31, max(0, (int)(s * (1.0f / 64.0f))));  // TT/32=64
        atomicAdd(&hist[b * 32 + sb], 1);
    }
    __syncthreads();

    const int a0  = hist[2 * tid];
    const int a1  = hist[2 * tid + 1];
    const int own = a0 + a1;
    int v = own;
    #pragma unroll
    for (int d = 1; d < 64; d <<= 1) {
        int u = __shfl_up(v, d, 64);
        if ((tid & 63) >= d) v += u;
    }
    if ((tid & 63) == 63) waveSums[tid >> 6] = v;
    __syncthreads();
    if (tid == 0) {
        int run = 0;
        #pragma unroll
        for (int i = 0; i < 4; ++i) { int c = waveSums[i]; waveSums[i] = run; run += c; }
    }
    __syncthreads();
    const int excl = v - own + waveSums[tid >> 6];
    hist[2 * tid]     = excl;
    hist[2 * tid + 1] = excl + a0;
    __syncthreads();

    for (int n = tid; n < N; n += 256) {
        const int   b  = (int)rois[3 * n];
        const float s  = rois[3 * n + 1];
        const int   sb = min(31, max(0, (int)(s * (1.0f / 64.0f))));
        const int pos = atomicAdd(&hist[b * 32 + sb], 1);
        perm[pos] = n;
    }
}

// ---------------------------------------------------------------------------
// Transpose (BS, CH, TT) f32 -> (BS, TT+1, CH) bf16 (row TT = dup of TT-1 so
// hi = lo+1 is unconditionally safe). Sort block folded in at blockIdx.z==BS.
// ---------------------------------------------------------------------------
__global__ __launch_bounds__(256) void ROIAlign_transpose_sort_kernel(
    const float* __restrict__ in, __hip_bfloat16* __restrict__ outT,
    const float* __restrict__ rois, int N, int* __restrict__ perm)
{
    const int tx = threadIdx.x;      // 0..31
    const int ty = threadIdx.y;      // 0..7

    if (blockIdx.z == BS) {
        if (blockIdx.x == 0 && blockIdx.y == 0 && perm)
            ROIAlign_sort_body(rois, N, perm, ty * 32 + tx);
        return;
    }

    __shared__ float tile[32][33];
    const int b  = blockIdx.z;
    const int t0 = blockIdx.x * 32;
    const int c0 = blockIdx.y * 32;

    const float* p = in + ((size_t)b * CH + c0) * TT + t0;
    #pragma unroll
    for (int i = ty; i < 32; i += 8)
        tile[i][tx] = p[(size_t)i * TT + tx];    // coalesced along t

    __syncthreads();

    __hip_bfloat16* q = outT + ((size_t)b * (TT + 1) + t0) * CH + c0;
    #pragma unroll
    for (int i = ty; i < 32; i += 8)
        q[(size_t)i * CH + tx] = __float2bfloat16(tile[tx][i]);
    if (t0 == TT - 32 && ty == 7)
        q[(size_t)32 * CH + tx] = __float2bfloat16(tile[tx][31]); // pad row TT
}

// ---------------------------------------------------------------------------
// Main kernel, fd==32, ratio==2 fast path, bf16 gather rows (512B each).
// Gather phase unchanged from R5 (read line-tx already at floor). New: LDS
// transpose epilogue. R5's direct stores were float4 @ 1KB lane stride =
// 64 line-tx per instruction (2048/block) -> 2/3 of all TA transactions.
// Now: acc -> 32KB swizzled LDS -> 8 contiguous 1KB wave-stores per wave
// (512 line-tx/block, the compulsory floor). Swizzle col = qf ^ (lc&7)
// keeps each b128 LDS phase <=2-way bank-aliased (free, m136).
// ---------------------------------------------------------------------------
__global__ __launch_bounds__(256) void ROIAlign_fd32_kernel(
    const __hip_bfloat16* __restrict__ inT,   // (BS, TT+1, CH) bf16
    const float* __restrict__ rois,           // (N, 3)
    const int*   __restrict__ ratio_p,
    const int*   __restrict__ perm,           // may be null
    float*       __restrict__ out)            // (N, CH, 32) f32
{
    __shared__ float4 ldsT[CH * 8];           // [c][qf^swz], 32 KB

    int m;
    if (perm) {
        const int chunk = gridDim.x >> 3;     // XCD-contiguous mapping
        const int sidx  = (blockIdx.x & 7) * chunk + (blockIdx.x >> 3);
        m = perm[sidx];
    } else {
        m = blockIdx.x;
    }
    const int tid = threadIdx.x;

    const int   b      = (int)rois[3 * m + 0];
    const float bstart = rois[3 * m + 1];
    const float bend   = rois[3 * m + 2];
    const float roi_len = fmaxf(bend - bstart, 1.0f);
    const float binsz   = roi_len * (1.0f / 32.0f);
    const int   ratio   = ratio_p[0];

    if (ratio == 2) {
        const int w    = tid >> 6;            // wave -> f-bin block
        const int l    = tid & 63;
        const int half = l >> 5;              // 0: bins +0..3, 1: bins +4..7
        const int lc   = l & 31;              // channel block: ch 8lc..8lc+7

        const unsigned short* base =
            (const unsigned short*)inT + (size_t)b * (TT + 1) * CH + 8 * lc;

        float acc[4][8];
        #pragma unroll
        for (int g = 0; g < 4; ++g)
            #pragma unroll
            for (int j = 0; j < 8; ++j) acc[g][j] = 0.0f;

        #pragma unroll
        for (int g = 0; g < 4; ++g) {
            const float fbin = (float)(w * 8 + half * 4 + g);
            #pragma unroll
            for (int r = 0; r < 2; ++r) {
                const float t  = bstart + (fbin + (r ? 0.75f : 0.25f)) * binsz;
                const float wv = (t >= -1.0f && t <= (float)TT) ? 0.5f : 0.0f;
                float tc = fminf(fmaxf(t, 0.0f), (float)(TT - 1));
                int   lo = (int)tc;           // tc>=0: trunc==floor
                float fr = tc - (float)lo;
                // hi = lo+1 always valid: row TT duplicates TT-1
                const ushortv8 ulo = *(const ushortv8*)(base + (size_t)lo * CH);
                const ushortv8 uhi = *(const ushortv8*)(base + (size_t)(lo + 1) * CH);
                #pragma unroll
                for (int j = 0; j < 8; ++j) {
                    const float vl = __uint_as_float((unsigned)ulo[j] << 16);
                    const float vh = __uint_as_float((unsigned)uhi[j] << 16);
                    acc[g][j] += wv * (vl + fr * (vh - vl));
                }
            }
        }

        // ---- epilogue: LDS transpose -> fully coalesced 1KB wave-stores ----
        const int qf = 2 * w + half;          // bin-quad index 0..7 (f = 4qf+g)
        #pragma unroll
        for (int j = 0; j < 8; ++j) {
            ldsT[(8 * lc + j) * 8 + (qf ^ (lc & 7))] =
                make_float4(acc[0][j], acc[1][j], acc[2][j], acc[3][j]);
        }
        __syncthreads();

        float4* ob = (float4*)(out + (size_t)m * (CH * 32));
        #pragma unroll
        for (int s = 0; s < 8; ++s) {
            const int k = w * 8 + s;          // channels 8k..8k+7, all bins
            const float4 v =
                ldsT[(8 * k + (l >> 3)) * 8 + ((l & 7) ^ (k & 7))];
            ob[64 * k + l] = v;               // contiguous 1KB per wave-store
        }
    } else {
        // generic-ratio path: thread = channel, scalar bf16 taps
        const int c = tid;
        const float inv_ratio = 1.0f / (float)ratio;
        const unsigned short* base =
            (const unsigned short*)inT + (size_t)b * (TT + 1) * CH + c;
        for (int f = 0; f < 32; ++f) {
            float a = 0.0f;
            for (int r = 0; r < ratio; ++r) {
                const float off = (float)f + ((float)r + 0.5f) * inv_ratio;
                const float t   = bstart + off * binsz;
                if (t >= -1.0f && t <= (float)TT) {
                    float tc = fminf(fmaxf(t, 0.0f), (float)(TT - 1));
                    int   lo = (int)tc;
                    float fr = tc - (float)lo;
                    const float vl = __uint_as_float((unsigned)base[(size_t)lo * CH] << 16);
                    const float vh = __uint_as_float((unsigned)base[(size_t)(lo + 1) * CH] << 16);
                    a += vl * (1.0f - fr) + vh * fr;
                }
            }
            out[((size_t)m * CH + c) * 32 + f] = a * inv_ratio;
        }
    }
}

// ---------------------------------------------------------------------------
// Generic fallback (any fd, no transpose, reads original f32 layout).
// ---------------------------------------------------------------------------
__global__ __launch_bounds__(256) void ROIAlign_generic_kernel(
    const float* __restrict__ in,      // (BS, CH, TT)
    const float* __restrict__ rois,
    const int*   __restrict__ ratio_p,
    float*       __restrict__ out,     // (N, CH, fd)
    int fd)
{
    const int n = blockIdx.x;
    const int   ratio     = ratio_p[0];
    const float inv_ratio = 1.0f / (float)ratio;

    const int   b      = (int)rois[3 * n + 0];
    const float bstart = rois[3 * n + 1];
    const float bend   = rois[3 * n + 2];
    const float roi_len = fmaxf(bend - bstart, 1.0f);
    const float bin     = roi_len / (float)fd;

    const int total = CH * fd;
    for (int idx = threadIdx.x; idx < total; idx += blockDim.x) {
        const int c = idx / fd;
        const int f = idx % fd;
        const float* base = in + ((size_t)b * CH + c) * TT;
        float a = 0.0f;
        for (int r = 0; r < ratio; ++r) {
            const float off = (float)f + ((float)r + 0.5f) * inv_ratio;
            const float t   = bstart + off * bin;
            if (t >= -1.0f && t <= (float)TT) {
                float tc = fminf(fmaxf(t, 0.0f), (float)(TT - 1));
                int   lo = (int)tc;
                int   hi = min(lo + 1, TT - 1);
                float fr = tc - (float)lo;
                a += base[lo] * (1.0f - fr) + base[hi] * fr;
            }
        }
        out[(size_t)n * total + idx] = a * inv_ratio;
    }
}

extern "C" void kernel_launch(void* const* d_in, const int* in_sizes, int n_in,
                              void* d_out, int out_size, void* d_ws, size_t ws_size,
                              hipStream_t stream) {
    const float* in      = (const float*)d_in[0];
    const float* rois    = (const float*)d_in[1];
    const int*   ratio_p = (const int*)d_in[3];
    float*       out     = (float*)d_out;

    const int N  = in_sizes[1] / 3;
    const int fd = out_size / (N * CH);
    const size_t transpose_bytes = (size_t)BS * (TT + 1) * CH * sizeof(__hip_bfloat16);
    const size_t perm_bytes      = (size_t)N * sizeof(int);

    const bool fast = (fd == 32) &&
                      (ws_size >= transpose_bytes + perm_bytes) &&
                      (in_sizes[0] == BS * CH * TT);

    if (fast) {
        __hip_bfloat16* inT = (__hip_bfloat16*)d_ws;
        const bool sorted = (N % 8 == 0) && (N <= 1 << 20);
        int* perm = sorted ? (int*)((char*)d_ws + transpose_bytes) : nullptr;

        dim3 tb(32, 8, 1);
        dim3 tg(TT / 32, CH / 32, BS + (sorted ? 1 : 0));
        hipLaunchKernelGGL(ROIAlign_transpose_sort_kernel, tg, tb, 0, stream,
                           in, inT, rois, N, perm);
        hipLaunchKernelGGL(ROIAlign_fd32_kernel, dim3(N), dim3(256), 0, stream,
                           inT, rois, ratio_p, perm, out);
    } else {
        hipLaunchKernelGGL(ROIAlign_generic_kernel, dim3(N), dim3(256), 0, stream,
                           in, rois, ratio_p, out, fd);
    }
}

// Round 7
// 47.599 us; speedup vs baseline: 1.7302x; 1.0427x over previous
//
#include <hip/hip_runtime.h>
#include <hip/hip_bf16.h>

#define BS 16
#define CH 256
#define TT 2048
#define NBINS 512   // 16 batches x 32 start-buckets

typedef unsigned short ushortv8 __attribute__((ext_vector_type(8)));

// ---------------------------------------------------------------------------
// Sort body: bin ROIs by (batch, start-bucket). 256 threads, one block.
// Within-bin order is atomic-arrival (nondeterministic) but each ROI's output
// is order-independent -> d_out deterministic.
// ---------------------------------------------------------------------------
__device__ void ROIAlign_sort_body(const float* __restrict__ rois, int N,
                                   int* __restrict__ perm, int tid)
{
    __shared__ int hist[NBINS];
    __shared__ int waveSums[4];

    for (int i = tid; i < NBINS; i += 256) hist[i] = 0;
    __syncthreads();

    for (int n = tid; n < N; n += 256) {
        const int   b  = (int)rois[3 * n];
        const float s  = rois[3 * n + 1];
        const int   sb = min(31, max(0, (int)(s * (1.0f / 64.0f))));  // TT/32=64
        atomicAdd(&hist[b * 32 + sb], 1);
    }
    __syncthreads();

    const int a0  = hist[2 * tid];
    const int a1  = hist[2 * tid + 1];
    const int own = a0 + a1;
    int v = own;
    #pragma unroll
    for (int d = 1; d < 64; d <<= 1) {
        int u = __shfl_up(v, d, 64);
        if ((tid & 63) >= d) v += u;
    }
    if ((tid & 63) == 63) waveSums[tid >> 6] = v;
    __syncthreads();
    if (tid == 0) {
        int run = 0;
        #pragma unroll
        for (int i = 0; i < 4; ++i) { int c = waveSums[i]; waveSums[i] = run; run += c; }
    }
    __syncthreads();
    const int excl = v - own + waveSums[tid >> 6];
    hist[2 * tid]     = excl;
    hist[2 * tid + 1] = excl + a0;
    __syncthreads();

    for (int n = tid; n < N; n += 256) {
        const int   b  = (int)rois[3 * n];
        const float s  = rois[3 * n + 1];
        const int   sb = min(31, max(0, (int)(s * (1.0f / 64.0f))));
        const int pos = atomicAdd(&hist[b * 32 + sb], 1);
        perm[pos] = n;
    }
}

// ---------------------------------------------------------------------------
// Transpose (BS, CH, TT) f32 -> (BS, TT+1, CH) bf16 (row TT dups TT-1).
// Vectorized: 64t x 64c tile, 256 threads, float4 global reads, ushort8
// stores (R6 version used scalar loads + 2B stores -> instruction-bound,
// ~42M mem-instrs; this is ~2x fewer with 8x wider stores). LDS tile[64][65]:
// all access phases <=2-way bank-aliased (free). Sort block at blockIdx.z==BS.
// ---------------------------------------------------------------------------
__global__ __launch_bounds__(256) void ROIAlign_transpose_sort_kernel(
    const float* __restrict__ in, __hip_bfloat16* __restrict__ outT,
    const float* __restrict__ rois, int N, int* __restrict__ perm)
{
    const int tid = threadIdx.x;

    if (blockIdx.z == BS) {
        if (blockIdx.x == 0 && blockIdx.y == 0 && perm)
            ROIAlign_sort_body(rois, N, perm, tid);
        return;
    }

    __shared__ float tile[64][65];   // [c][t], odd row stride: <=2-way banks
    const int b  = blockIdx.z;
    const int t0 = blockIdx.x * 64;
    const int c0 = blockIdx.y * 64;

    // read: thread -> c-row r = tid>>2, t-chunk q = tid&3 (16 floats via 4xfloat4)
    {
        const int r = tid >> 2;
        const int q = tid & 3;
        const float* p = in + ((size_t)(b * CH + c0 + r)) * TT + t0 + q * 16;
        #pragma unroll
        for (int i = 0; i < 4; ++i) {
            const float4 f4 = *(const float4*)(p + 4 * i);
            tile[r][q * 16 + 4 * i + 0] = f4.x;
            tile[r][q * 16 + 4 * i + 1] = f4.y;
            tile[r][q * 16 + 4 * i + 2] = f4.z;
            tile[r][q * 16 + 4 * i + 3] = f4.w;
        }
    }
    __syncthreads();

    // write: thread -> ch-oct o = tid&7, t-row rr = tid>>3 (+32 per pass)
    {
        const int o  = tid & 7;
        const int rr = tid >> 3;
        #pragma unroll
        for (int p2 = 0; p2 < 2; ++p2) {
            const int rp = rr + 32 * p2;
            ushortv8 u;
            #pragma unroll
            for (int k = 0; k < 8; ++k)
                u[k] = __bfloat16_as_ushort(__float2bfloat16(tile[8 * o + k][rp]));
            *(ushortv8*)((unsigned short*)outT +
                ((size_t)b * (TT + 1) + t0 + rp) * CH + c0 + 8 * o) = u;
            if (t0 == TT - 64 && rp == 63) {      // pad row TT = dup of TT-1
                *(ushortv8*)((unsigned short*)outT +
                    ((size_t)b * (TT + 1) + TT) * CH + c0 + 8 * o) = u;
            }
        }
    }
}

// ---------------------------------------------------------------------------
// Main kernel, fd==32, ratio==2 fast path, bf16 gather rows (512B each).
// Thread (wave w, half, lane lc) owns bins f = 4*qf+g, qf = w + 4*half,
// channels 8lc..8lc+7. Gather: one 64-lane ushort8 load covers two 512B rows.
// Epilogue: TWO 16KB LDS phases (qf<4 then qf>=4) -> 8 blocks/CU (R6's 32KB
// buffer capped occupancy at 5). XOR-swizzled buf[128][8]: <=4-way both sides.
// Stores: 16 full 64B lines per instruction (compulsory floor).
// ---------------------------------------------------------------------------
__global__ __launch_bounds__(256) void ROIAlign_fd32_kernel(
    const __hip_bfloat16* __restrict__ inT,   // (BS, TT+1, CH) bf16
    const float* __restrict__ rois,           // (N, 3)
    const int*   __restrict__ ratio_p,
    const int*   __restrict__ perm,           // may be null
    float*       __restrict__ out)            // (N, CH, 32) f32
{
    __shared__ float4 buf[128][8];            // 16 KB

    int m;
    if (perm) {
        const int chunk = gridDim.x >> 3;     // XCD-contiguous mapping
        const int sidx  = (blockIdx.x & 7) * chunk + (blockIdx.x >> 3);
        m = perm[sidx];
    } else {
        m = blockIdx.x;
    }
    const int tid = threadIdx.x;

    const int   b      = (int)rois[3 * m + 0];
    const float bstart = rois[3 * m + 1];
    const float bend   = rois[3 * m + 2];
    const float roi_len = fmaxf(bend - bstart, 1.0f);
    const float binsz   = roi_len * (1.0f / 32.0f);
    const int   ratio   = ratio_p[0];

    if (ratio == 2) {
        const int w    = tid >> 6;            // wave
        const int l    = tid & 63;
        const int half = l >> 5;              // qf = w + 4*half
        const int lc   = l & 31;              // channels 8lc..8lc+7

        const unsigned short* base =
            (const unsigned short*)inT + (size_t)b * (TT + 1) * CH + 8 * lc;

        float acc[4][8];
        #pragma unroll
        for (int g = 0; g < 4; ++g)
            #pragma unroll
            for (int j = 0; j < 8; ++j) acc[g][j] = 0.0f;

        #pragma unroll
        for (int g = 0; g < 4; ++g) {
            const float fbin = (float)(4 * w + 16 * half + g);   // f = 4*qf+g
            #pragma unroll
            for (int r = 0; r < 2; ++r) {
                const float t  = bstart + (fbin + (r ? 0.75f : 0.25f)) * binsz;
                const float wv = (t >= -1.0f && t <= (float)TT) ? 0.5f : 0.0f;
                float tc = fminf(fmaxf(t, 0.0f), (float)(TT - 1));
                int   lo = (int)tc;           // tc>=0: trunc==floor
                float fr = tc - (float)lo;
                // hi = lo+1 always valid: row TT duplicates TT-1
                const ushortv8 ulo = *(const ushortv8*)(base + (size_t)lo * CH);
                const ushortv8 uhi = *(const ushortv8*)(base + (size_t)(lo + 1) * CH);
                #pragma unroll
                for (int j = 0; j < 8; ++j) {
                    const float vl = __uint_as_float((unsigned)ulo[j] << 16);
                    const float vh = __uint_as_float((unsigned)uhi[j] << 16);
                    acc[g][j] += wv * (vl + fr * (vh - vl));
                }
            }
        }

        // ---- two-phase LDS transpose epilogue (16 KB) ----
        float4* ob = (float4*)(out + (size_t)m * (CH * 32));
        #pragma unroll
        for (int p = 0; p < 2; ++p) {
            if (p) __syncthreads();           // phase-0 reads done before rewrite
            if (half == p) {
                #pragma unroll
                for (int j = 0; j < 8; ++j) {
                    const int ch = 8 * lc + j;
                    buf[ch >> 1][((ch & 1) * 4 + w) ^ (lc & 7)] =
                        make_float4(acc[0][j], acc[1][j], acc[2][j], acc[3][j]);
                }
            }
            __syncthreads();
            #pragma unroll
            for (int s = 0; s < 4; ++s) {
                const int ch  = 64 * w + 16 * s + (l >> 2);
                const int qfc = l & 3;        // absolute qf = 4p + qfc
                const float4 v =
                    buf[ch >> 1][((ch & 1) * 4 + qfc) ^ ((ch >> 3) & 7)];
                ob[(size_t)ch * 8 + 4 * p + qfc] = v;
            }
        }
    } else {
        // generic-ratio path: thread = channel, scalar bf16 taps
        const int c = tid;
        const float inv_ratio = 1.0f / (float)ratio;
        const unsigned short* base =
            (const unsigned short*)inT + (size_t)b * (TT + 1) * CH + c;
        for (int f = 0; f < 32; ++f) {
            float a = 0.0f;
            for (int r = 0; r < ratio; ++r) {
                const float off = (float)f + ((float)r + 0.5f) * inv_ratio;
                const float t   = bstart + off * binsz;
                if (t >= -1.0f && t <= (float)TT) {
                    float tc = fminf(fmaxf(t, 0.0f), (float)(TT - 1));
                    int   lo = (int)tc;
                    float fr = tc - (float)lo;
                    const float vl = __uint_as_float((unsigned)base[(size_t)lo * CH] << 16);
                    const float vh = __uint_as_float((unsigned)base[(size_t)(lo + 1) * CH] << 16);
                    a += vl * (1.0f - fr) + vh * fr;
                }
            }
            out[((size_t)m * CH + c) * 32 + f] = a * inv_ratio;
        }
    }
}

// ---------------------------------------------------------------------------
// Generic fallback (any fd, no transpose, reads original f32 layout).
// ---------------------------------------------------------------------------
__global__ __launch_bounds__(256) void ROIAlign_generic_kernel(
    const float* __restrict__ in,      // (BS, CH, TT)
    const float* __restrict__ rois,
    const int*   __restrict__ ratio_p,
    float*       __restrict__ out,     // (N, CH, fd)
    int fd)
{
    const int n = blockIdx.x;
    const int   ratio     = ratio_p[0];
    const float inv_ratio = 1.0f / (float)ratio;

    const int   b      = (int)rois[3 * n + 0];
    const float bstart = rois[3 * n + 1];
    const float bend   = rois[3 * n + 2];
    const float roi_len = fmaxf(bend - bstart, 1.0f);
    const float bin     = roi_len / (float)fd;

    const int total = CH * fd;
    for (int idx = threadIdx.x; idx < total; idx += blockDim.x) {
        const int c = idx / fd;
        const int f = idx % fd;
        const float* base = in + ((size_t)b * CH + c) * TT;
        float a = 0.0f;
        for (int r = 0; r < ratio; ++r) {
            const float off = (float)f + ((float)r + 0.5f) * inv_ratio;
            const float t   = bstart + off * bin;
            if (t >= -1.0f && t <= (float)TT) {
                float tc = fminf(fmaxf(t, 0.0f), (float)(TT - 1));
                int   lo = (int)tc;
                int   hi = min(lo + 1, TT - 1);
                float fr = tc - (float)lo;
                a += base[lo] * (1.0f - fr) + base[hi] * fr;
            }
        }
        out[(size_t)n * total + idx] = a * inv_ratio;
    }
}

extern "C" void kernel_launch(void* const* d_in, const int* in_sizes, int n_in,
                              void* d_out, int out_size, void* d_ws, size_t ws_size,
                              hipStream_t stream) {
    const float* in      = (const float*)d_in[0];
    const float* rois    = (const float*)d_in[1];
    const int*   ratio_p = (const int*)d_in[3];
    float*       out     = (float*)d_out;

    const int N  = in_sizes[1] / 3;
    const int fd = out_size / (N * CH);
    const size_t transpose_bytes = (size_t)BS * (TT + 1) * CH * sizeof(__hip_bfloat16);
    const size_t perm_bytes      = (size_t)N * sizeof(int);

    const bool fast = (fd == 32) &&
                      (ws_size >= transpose_bytes + perm_bytes) &&
                      (in_sizes[0] == BS * CH * TT);

    if (fast) {
        __hip_bfloat16* inT = (__hip_bfloat16*)d_ws;
        const bool sorted = (N % 8 == 0) && (N <= 1 << 20);
        int* perm = sorted ? (int*)((char*)d_ws + transpose_bytes) : nullptr;

        dim3 tg(TT / 64, CH / 64, BS + (sorted ? 1 : 0));
        hipLaunchKernelGGL(ROIAlign_transpose_sort_kernel, tg, dim3(256), 0, stream,
                           in, inT, rois, N, perm);
        hipLaunchKernelGGL(ROIAlign_fd32_kernel, dim3(N), dim3(256), 0, stream,
                           inT, rois, ratio_p, perm, out);
    } else {
        hipLaunchKernelGGL(ROIAlign_generic_kernel, dim3(N), dim3(256), 0, stream,
                           in, rois, ratio_p, out, fd);
    }
}